// Round 1
// baseline (191.496 us; speedup 1.0000x reference)
//
#include <hip/hip_runtime.h>

#define DEV_INLINE static __device__ __forceinline__

typedef __attribute__((ext_vector_type(8))) short bf16x8;
typedef __attribute__((ext_vector_type(4))) float f32x4;

DEV_INLINE unsigned short f2bf(float f) {
  union { float f; unsigned int u; } v; v.f = f;
  unsigned int u = v.u;
  u += 0x7FFFu + ((u >> 16) & 1u);   // RNE
  return (unsigned short)(u >> 16);
}
DEV_INLINE float bf2f(unsigned short h) {
  union { unsigned int u; float f; } v; v.u = ((unsigned int)h) << 16; return v.f;
}

// ---------------- fp32 -> bf16 conversion ----------------
__global__ __launch_bounds__(256) void cvt_f32_bf16(const float* __restrict__ in,
                                                    unsigned short* __restrict__ out, int n4) {
  int i = blockIdx.x * 256 + threadIdx.x;
  if (i >= n4) return;
  float4 v = reinterpret_cast<const float4*>(in)[i];
  ushort4 o;
  o.x = f2bf(v.x); o.y = f2bf(v.y); o.z = f2bf(v.z); o.w = f2bf(v.w);
  reinterpret_cast<ushort4*>(out)[i] = o;
}

// ---------------- GEMM: C[M,N] = A[M,768] * B[N,768]^T (+bias) ----------------
// MODE 0: qkv projection, scatter bf16 into q/k/v [48][1024][64]
// MODE 1: output projection, fp32 out [4096][768]
template <int MODE>
__global__ __launch_bounds__(256) void gemm_bf16(const unsigned short* __restrict__ A,
                                                 const unsigned short* __restrict__ Bw,
                                                 const float* __restrict__ bias,
                                                 float* __restrict__ outF,
                                                 unsigned short* __restrict__ qo,
                                                 unsigned short* __restrict__ ko,
                                                 unsigned short* __restrict__ vo) {
  __shared__ unsigned short As[128 * 40];
  __shared__ unsigned short Bs[128 * 40];

  const int tid = threadIdx.x;
  const int lane = tid & 63;
  const int wv = tid >> 6;
  const int wrow = (wv >> 1) * 64;
  const int wcol = (wv & 1) * 64;
  const int m0 = blockIdx.y * 128;
  const int n0 = blockIdx.x * 128;
  const int l15 = lane & 15;
  const int lg = lane >> 4;
  const int koff = lg * 8;

  f32x4 acc[4][4];
#pragma unroll
  for (int i = 0; i < 4; ++i)
#pragma unroll
    for (int j = 0; j < 4; ++j) acc[i][j] = (f32x4){0.f, 0.f, 0.f, 0.f};

  for (int kt = 0; kt < 768; kt += 32) {
    __syncthreads();
#pragma unroll
    for (int i = 0; i < 2; ++i) {
      int s = tid + i * 256;          // 512 segs of 8 bf16 per tile
      int row = s >> 2, sc = (s & 3) * 8;
      *reinterpret_cast<int4*>(&As[row * 40 + sc]) =
          *reinterpret_cast<const int4*>(&A[(m0 + row) * 768 + kt + sc]);
      *reinterpret_cast<int4*>(&Bs[row * 40 + sc]) =
          *reinterpret_cast<const int4*>(&Bw[(n0 + row) * 768 + kt + sc]);
    }
    __syncthreads();

    bf16x8 aF[4], bF[4];
#pragma unroll
    for (int i = 0; i < 4; ++i)
      aF[i] = *reinterpret_cast<const bf16x8*>(&As[(wrow + i * 16 + l15) * 40 + koff]);
#pragma unroll
    for (int j = 0; j < 4; ++j)
      bF[j] = *reinterpret_cast<const bf16x8*>(&Bs[(wcol + j * 16 + l15) * 40 + koff]);
#pragma unroll
    for (int i = 0; i < 4; ++i)
#pragma unroll
      for (int j = 0; j < 4; ++j)
        acc[i][j] = __builtin_amdgcn_mfma_f32_16x16x32_bf16(aF[i], bF[j], acc[i][j], 0, 0, 0);
  }

#pragma unroll
  for (int i = 0; i < 4; ++i) {
#pragma unroll
    for (int j = 0; j < 4; ++j) {
#pragma unroll
      for (int r = 0; r < 4; ++r) {
        int row = m0 + wrow + i * 16 + lg * 4 + r;
        int col = n0 + wcol + j * 16 + l15;
        float val = acc[i][j][r] + bias[col];
        if (MODE == 0) {
          int t = col / 768;
          int rem = col - t * 768;
          int head = rem >> 6;
          int c = rem & 63;
          int bb = row >> 10;
          int n = row & 1023;
          unsigned short* dst = (t == 0) ? qo : (t == 1) ? ko : vo;
          dst[((bb * 12 + head) * 1024 + n) * 64 + c] = f2bf(val);
        } else {
          outF[row * 768 + col] = val;
        }
      }
    }
  }
}

// ---------------- decomposed rel-pos terms ----------------
// relh[bh, qh*32+qw, kh] = sum_c q[bh, qh*32+qw, c] * rel_pos_h[qh-kh+31, c]
// relw[bh, qh*32+qw, kw] = sum_c q[bh, qh*32+qw, c] * rel_pos_w[qw-kw+31, c]
__global__ __launch_bounds__(256) void rel_kernel(const unsigned short* __restrict__ q,
                                                  const float* __restrict__ rph,
                                                  const float* __restrict__ rpw,
                                                  float* __restrict__ relh,
                                                  float* __restrict__ relw) {
  __shared__ unsigned short qs[32 * 64];
  __shared__ float rh_s[32 * 65];
  __shared__ float rw_s[63 * 65];

  const int bh = blockIdx.x >> 5;
  const int qh = blockIdx.x & 31;
  const int tid = threadIdx.x;

#pragma unroll
  for (int i = 0; i < 2; ++i) {     // 32x64 bf16 = 512 x ushort4
    int s = tid + i * 256;
    reinterpret_cast<ushort4*>(qs)[s] =
        reinterpret_cast<const ushort4*>(q + (bh * 1024 + qh * 32) * 64)[s];
  }
#pragma unroll
  for (int i = 0; i < 2; ++i) {     // rows qh..qh+31, 512 float4
    int s = tid + i * 256;
    int row = s >> 4, c4 = (s & 15) * 4;
    float4 vv = *reinterpret_cast<const float4*>(&rph[(qh + row) * 64 + c4]);
    rh_s[row * 65 + c4 + 0] = vv.x;
    rh_s[row * 65 + c4 + 1] = vv.y;
    rh_s[row * 65 + c4 + 2] = vv.z;
    rh_s[row * 65 + c4 + 3] = vv.w;
  }
#pragma unroll
  for (int i = 0; i < 4; ++i) {     // 63 rows, 1008 float4
    int s = tid + i * 256;
    if (s < 1008) {
      int row = s >> 4, c4 = (s & 15) * 4;
      float4 vv = *reinterpret_cast<const float4*>(&rpw[row * 64 + c4]);
      rw_s[row * 65 + c4 + 0] = vv.x;
      rw_s[row * 65 + c4 + 1] = vv.y;
      rw_s[row * 65 + c4 + 2] = vv.z;
      rw_s[row * 65 + c4 + 3] = vv.w;
    }
  }
  __syncthreads();

#pragma unroll
  for (int i = 0; i < 4; ++i) {
    int oid = tid + i * 256;
    int qw = oid >> 5, kh = oid & 31;
    const unsigned short* qrow = &qs[qw * 64];
    const float* rr = &rh_s[(31 - kh) * 65];
    float a = 0.f;
#pragma unroll
    for (int c = 0; c < 64; ++c) a += bf2f(qrow[c]) * rr[c];
    relh[(bh * 1024 + qh * 32 + qw) * 32 + kh] = a;
  }
#pragma unroll
  for (int i = 0; i < 4; ++i) {
    int oid = tid + i * 256;
    int qw = oid >> 5, kw = oid & 31;
    const unsigned short* qrow = &qs[qw * 64];
    const float* rr = &rw_s[(qw - kw + 31) * 65];
    float a = 0.f;
#pragma unroll
    for (int c = 0; c < 64; ++c) a += bf2f(qrow[c]) * rr[c];
    relw[(bh * 1024 + qh * 32 + qw) * 32 + kw] = a;
  }
}

// ---------------- flash attention with decomposed bias ----------------
__global__ __launch_bounds__(256) void attn_kernel(const unsigned short* __restrict__ q,
                                                   const unsigned short* __restrict__ k,
                                                   const unsigned short* __restrict__ v,
                                                   const float* __restrict__ relh,
                                                   const float* __restrict__ relw,
                                                   unsigned short* __restrict__ ao) {
  __shared__ unsigned short k_s[64 * 72];
  __shared__ unsigned short vt_s[64 * 72];
  __shared__ float rh_s[64 * 33];
  __shared__ float rw_s[64 * 33];
  __shared__ unsigned short p_s[4][16 * 72];

  const int bh = blockIdx.y;
  const int qt = blockIdx.x;
  const int tid = threadIdx.x;
  const int lane = tid & 63;
  const int wv = tid >> 6;
  const int l15 = lane & 15;
  const int lg = lane >> 4;
  const int koff = lg * 8;

  {  // stage rel rows for the 64 q rows of this block
    const float* src_h = &relh[(bh * 1024 + qt * 64) * 32];
    const float* src_w = &relw[(bh * 1024 + qt * 64) * 32];
#pragma unroll
    for (int i = 0; i < 2; ++i) {
      int s = tid + i * 256;        // 512 float4 each
      int row = s >> 3, c4 = (s & 7) * 4;
      float4 vv = *reinterpret_cast<const float4*>(&src_h[row * 32 + c4]);
      rh_s[row * 33 + c4 + 0] = vv.x;
      rh_s[row * 33 + c4 + 1] = vv.y;
      rh_s[row * 33 + c4 + 2] = vv.z;
      rh_s[row * 33 + c4 + 3] = vv.w;
      float4 ww = *reinterpret_cast<const float4*>(&src_w[row * 32 + c4]);
      rw_s[row * 33 + c4 + 0] = ww.x;
      rw_s[row * 33 + c4 + 1] = ww.y;
      rw_s[row * 33 + c4 + 2] = ww.z;
      rw_s[row * 33 + c4 + 3] = ww.w;
    }
  }

  const int qrow_g = bh * 1024 + qt * 64 + wv * 16 + l15;
  const bf16x8 qa0 = *reinterpret_cast<const bf16x8*>(&q[qrow_g * 64 + koff]);
  const bf16x8 qa1 = *reinterpret_cast<const bf16x8*>(&q[qrow_g * 64 + 32 + koff]);

  f32x4 O[4];
#pragma unroll
  for (int dg = 0; dg < 4; ++dg) O[dg] = (f32x4){0.f, 0.f, 0.f, 0.f};
  float m_r[4], l_r[4];
#pragma unroll
  for (int r = 0; r < 4; ++r) { m_r[r] = -3.0e38f; l_r[r] = 0.f; }

  for (int kt = 0; kt < 16; ++kt) {
    __syncthreads();
#pragma unroll
    for (int i = 0; i < 2; ++i) {   // K tile: 512 segs of 8 bf16
      int s = tid + i * 256;
      int row = s >> 3, sc = (s & 7) * 8;
      *reinterpret_cast<int4*>(&k_s[row * 72 + sc]) =
          *reinterpret_cast<const int4*>(&k[(bh * 1024 + kt * 64 + row) * 64 + sc]);
    }
#pragma unroll
    for (int i = 0; i < 4; ++i) {   // V tile transposed: 1024 segs of 4
      int s = tid + i * 256;
      int key = s >> 4, quad = (s & 15) * 4;
      ushort4 vv = *reinterpret_cast<const ushort4*>(&v[(bh * 1024 + kt * 64 + key) * 64 + quad]);
      vt_s[(quad + 0) * 72 + key] = vv.x;
      vt_s[(quad + 1) * 72 + key] = vv.y;
      vt_s[(quad + 2) * 72 + key] = vv.z;
      vt_s[(quad + 3) * 72 + key] = vv.w;
    }
    __syncthreads();

    // S = scale * Q K^T + bias
    f32x4 sv[4];
#pragma unroll
    for (int g = 0; g < 4; ++g) {
      bf16x8 kb0 = *reinterpret_cast<const bf16x8*>(&k_s[(g * 16 + l15) * 72 + koff]);
      bf16x8 kb1 = *reinterpret_cast<const bf16x8*>(&k_s[(g * 16 + l15) * 72 + 32 + koff]);
      f32x4 a = (f32x4){0.f, 0.f, 0.f, 0.f};
      a = __builtin_amdgcn_mfma_f32_16x16x32_bf16(qa0, kb0, a, 0, 0, 0);
      a = __builtin_amdgcn_mfma_f32_16x16x32_bf16(qa1, kb1, a, 0, 0, 0);
      sv[g] = a;
    }
#pragma unroll
    for (int g = 0; g < 4; ++g) {
      int key = kt * 64 + g * 16 + l15;
      int kh = key >> 5, kw = key & 31;
#pragma unroll
      for (int r = 0; r < 4; ++r) {
        int qr = wv * 16 + lg * 4 + r;
        sv[g][r] = sv[g][r] * 0.125f + rh_s[qr * 33 + kh] + rw_s[qr * 33 + kw];
      }
    }

    // online softmax
    float corr[4], psum[4];
#pragma unroll
    for (int r = 0; r < 4; ++r) {
      float t0 = fmaxf(fmaxf(sv[0][r], sv[1][r]), fmaxf(sv[2][r], sv[3][r]));
#pragma unroll
      for (int msk = 1; msk < 16; msk <<= 1) t0 = fmaxf(t0, __shfl_xor(t0, msk));
      float nm = fmaxf(m_r[r], t0);
      corr[r] = __expf(m_r[r] - nm);
      m_r[r] = nm;
      psum[r] = 0.f;
    }
#pragma unroll
    for (int g = 0; g < 4; ++g)
#pragma unroll
      for (int r = 0; r < 4; ++r) {
        float p = __expf(sv[g][r] - m_r[r]);
        sv[g][r] = p;
        psum[r] += p;
      }
#pragma unroll
    for (int r = 0; r < 4; ++r) {
#pragma unroll
      for (int msk = 1; msk < 16; msk <<= 1) psum[r] += __shfl_xor(psum[r], msk);
      l_r[r] = l_r[r] * corr[r] + psum[r];
    }
#pragma unroll
    for (int dg = 0; dg < 4; ++dg)
#pragma unroll
      for (int r = 0; r < 4; ++r) O[dg][r] *= corr[r];

    // P -> LDS (bf16), per-wave region
#pragma unroll
    for (int g = 0; g < 4; ++g)
#pragma unroll
      for (int r = 0; r < 4; ++r)
        p_s[wv][(lg * 4 + r) * 72 + g * 16 + l15] = f2bf(sv[g][r]);

    bf16x8 pa0 = *reinterpret_cast<const bf16x8*>(&p_s[wv][l15 * 72 + koff]);
    bf16x8 pa1 = *reinterpret_cast<const bf16x8*>(&p_s[wv][l15 * 72 + 32 + koff]);
#pragma unroll
    for (int dg = 0; dg < 4; ++dg) {
      bf16x8 vb0 = *reinterpret_cast<const bf16x8*>(&vt_s[(dg * 16 + l15) * 72 + koff]);
      bf16x8 vb1 = *reinterpret_cast<const bf16x8*>(&vt_s[(dg * 16 + l15) * 72 + 32 + koff]);
      O[dg] = __builtin_amdgcn_mfma_f32_16x16x32_bf16(pa0, vb0, O[dg], 0, 0, 0);
      O[dg] = __builtin_amdgcn_mfma_f32_16x16x32_bf16(pa1, vb1, O[dg], 0, 0, 0);
    }
  }

  const int bb = bh / 12, head = bh % 12;
#pragma unroll
  for (int r = 0; r < 4; ++r) {
    int n = qt * 64 + wv * 16 + lg * 4 + r;
    float inv = 1.f / l_r[r];
    unsigned short* dst = &ao[(bb * 1024 + n) * 768 + head * 64];
#pragma unroll
    for (int dg = 0; dg < 4; ++dg) dst[dg * 16 + l15] = f2bf(O[dg][r] * inv);
  }
}

extern "C" void kernel_launch(void* const* d_in, const int* in_sizes, int n_in,
                              void* d_out, int out_size, void* d_ws, size_t ws_size,
                              hipStream_t stream) {
  const float* x      = (const float*)d_in[0];
  const float* qkv_w  = (const float*)d_in[1];
  const float* qkv_b  = (const float*)d_in[2];
  const float* proj_w = (const float*)d_in[3];
  const float* proj_b = (const float*)d_in[4];
  const float* rph    = (const float*)d_in[5];
  const float* rpw    = (const float*)d_in[6];
  float* out = (float*)d_out;

  char* ws = (char*)d_ws;
  unsigned short* xb    = (unsigned short*)(ws);
  unsigned short* wqkv  = (unsigned short*)(ws + 6291456);
  unsigned short* wproj = (unsigned short*)(ws + 9830400);
  unsigned short* qb    = (unsigned short*)(ws + 11010048);
  unsigned short* kb    = (unsigned short*)(ws + 17301504);
  unsigned short* vb    = (unsigned short*)(ws + 23592960);
  float* relh           = (float*)(ws + 29884416);
  float* relw           = (float*)(ws + 36175872);
  unsigned short* ao    = (unsigned short*)(ws + 42467328);

  cvt_f32_bf16<<<3072, 256, 0, stream>>>(x, xb, 786432);
  cvt_f32_bf16<<<1728, 256, 0, stream>>>(qkv_w, wqkv, 442368);
  cvt_f32_bf16<<<576, 256, 0, stream>>>(proj_w, wproj, 147456);

  gemm_bf16<0><<<dim3(18, 32), 256, 0, stream>>>(xb, wqkv, qkv_b, nullptr, qb, kb, vb);
  rel_kernel<<<1536, 256, 0, stream>>>(qb, rph, rpw, relh, relw);
  attn_kernel<<<dim3(16, 48), 256, 0, stream>>>(qb, kb, vb, relh, relw, ao);
  gemm_bf16<1><<<dim3(6, 32), 256, 0, stream>>>(ao, wproj, proj_b, out, nullptr, nullptr, nullptr);
}